// Round 6
// baseline (15758.949 us; speedup 1.0000x reference)
//
#include <hip/hip_runtime.h>
#include <hip/hip_bf16.h>
#include <math.h>

#define ND 100000
#define NS 50000
#define NE1 500000
#define NE2 250000
#define DIM 128
#define NH 4
#define HDI 32
#define GRID_P 768   // 3 blocks/CU * 256 CUs

typedef __hip_bfloat16 bf16;
typedef unsigned short u16;
typedef unsigned int u32;

__device__ __forceinline__ float ldf(const float* p, size_t i) { return p[i]; }
__device__ __forceinline__ float ldf(const bf16* p, size_t i) { return __bfloat162float(p[i]); }
__device__ __forceinline__ void stf(float* p, size_t i, float v) { p[i] = v; }
__device__ __forceinline__ void stf(bf16* p, size_t i, float v) { p[i] = __float2bfloat16(v); }
__device__ __forceinline__ float b2f(bf16 v) { return __bfloat162float(v); }

__device__ __forceinline__ u16 f2bfu(float f) {
    __hip_bfloat16 h = __float2bfloat16(f);
    union { __hip_bfloat16 b; u16 u; } c; c.b = h; return c.u;
}
// unpack a bf16 pair (one dword, little-endian) to two floats
__device__ __forceinline__ float2 bfp(u32 u) {
    float2 r;
    r.x = __uint_as_float(u << 16);
    r.y = __uint_as_float(u & 0xffff0000u);
    return r;
}
// uniform-lane broadcast (compile-time lane after unroll -> v_readlane)
__device__ __forceinline__ float rlf(float v, int l) {
    return __uint_as_float(__builtin_amdgcn_readlane(__float_as_uint(v), l));
}

// ---------- diagnostics ----------
__global__ void fill16_kernel(u16* p, u16 v, size_t n) {
    size_t i = (size_t)blockIdx.x * blockDim.x + threadIdx.x;
    if (i < n) p[i] = v;
}

// flag=1 if float inputs are fp32, flag=0 if bf16 (sample EVEN ushorts = fp32
// low-mantissa halves; real bf16 weights never have exponent >= 0x90).
__global__ __launch_bounds__(64) void detect_kernel(const u16* w, int* flag) {
    int lane = threadIdx.x;
    int mx = 0;
    for (int j = 0; j < 32; ++j) {
        int i = 2 * (lane + 64 * j);
        int e = (w[i] >> 7) & 0xFF;
        mx = mx > e ? mx : e;
    }
    for (int d = 32; d; d >>= 1) { int o = __shfl_xor(mx, d); mx = mx > o ? mx : o; }
    if (lane == 0) flag[0] = (mx >= 0x90) ? 1 : 0;
}

// ---------- node projections: wave works 4 nodes/iter, LDS-staged bf16 weights ----------
template <typename T>
__device__ __forceinline__ void proj2_body(
    u16* W1s, u16* W2s,
    const T* X, const T* W1, const T* b1, const T* W2, const T* b2,
    bf16* Y1, bf16* Y2, int N)
{
    int tid = threadIdx.x;
    for (int i = tid; i < DIM * DIM; i += 256) {
        W1s[i] = f2bfu(ldf(W1, i));
        W2s[i] = f2bfu(ldf(W2, i));
    }
    __syncthreads();
    const u32* W1u = (const u32*)W1s;
    const u32* W2u = (const u32*)W2s;
    int lane = tid & 63, d0 = 2 * lane;
    float b10 = ldf(b1, d0), b11 = ldf(b1, d0 + 1);
    float b20 = ldf(b2, d0), b21 = ldf(b2, d0 + 1);
    int wid = blockIdx.x * 4 + (tid >> 6);
    for (int n = wid * 4; n <= N - 4; n += GRID_P * 16) {
        float xA[4], xB[4];
#pragma unroll
        for (int t = 0; t < 4; ++t) {
            xA[t] = ldf(X, (size_t)(n + t) * DIM + d0);
            xB[t] = ldf(X, (size_t)(n + t) * DIM + d0 + 1);
        }
        // W1 pass
        {
            float a0[4], a1[4];
#pragma unroll
            for (int t = 0; t < 4; ++t) { a0[t] = b10; a1[t] = b11; }
#pragma unroll
            for (int k2 = 0; k2 < 64; ++k2) {
                float2 wa = bfp(W1u[(2 * k2) * 64 + lane]);
                float2 wb = bfp(W1u[(2 * k2 + 1) * 64 + lane]);
#pragma unroll
                for (int t = 0; t < 4; ++t) {
                    float x0 = rlf(xA[t], k2), x1 = rlf(xB[t], k2);
                    a0[t] = fmaf(x0, wa.x, a0[t]); a1[t] = fmaf(x0, wa.y, a1[t]);
                    a0[t] = fmaf(x1, wb.x, a0[t]); a1[t] = fmaf(x1, wb.y, a1[t]);
                }
            }
#pragma unroll
            for (int t = 0; t < 4; ++t) {
                Y1[(size_t)(n + t) * DIM + d0]     = __float2bfloat16(a0[t]);
                Y1[(size_t)(n + t) * DIM + d0 + 1] = __float2bfloat16(a1[t]);
            }
        }
        // W2 pass
        {
            float a0[4], a1[4];
#pragma unroll
            for (int t = 0; t < 4; ++t) { a0[t] = b20; a1[t] = b21; }
#pragma unroll
            for (int k2 = 0; k2 < 64; ++k2) {
                float2 wa = bfp(W2u[(2 * k2) * 64 + lane]);
                float2 wb = bfp(W2u[(2 * k2 + 1) * 64 + lane]);
#pragma unroll
                for (int t = 0; t < 4; ++t) {
                    float x0 = rlf(xA[t], k2), x1 = rlf(xB[t], k2);
                    a0[t] = fmaf(x0, wa.x, a0[t]); a1[t] = fmaf(x0, wa.y, a1[t]);
                    a0[t] = fmaf(x1, wb.x, a0[t]); a1[t] = fmaf(x1, wb.y, a1[t]);
                }
            }
#pragma unroll
            for (int t = 0; t < 4; ++t) {
                Y2[(size_t)(n + t) * DIM + d0]     = __float2bfloat16(a0[t]);
                Y2[(size_t)(n + t) * DIM + d0 + 1] = __float2bfloat16(a1[t]);
            }
        }
    }
}

__global__ __launch_bounds__(256, 2) void proj2_kernel(
    const int* __restrict__ flag, const void* X,
    const void* W1, const void* b1, const void* W2, const void* b2,
    bf16* __restrict__ Y1, bf16* __restrict__ Y2, int N)
{
    __shared__ u16 W1s[DIM * DIM];
    __shared__ u16 W2s[DIM * DIM];
    if (flag[0]) proj2_body(W1s, W2s, (const float*)X, (const float*)W1, (const float*)b1,
                            (const float*)W2, (const float*)b2, Y1, Y2, N);
    else         proj2_body(W1s, W2s, (const bf16*)X, (const bf16*)W1, (const bf16*)b1,
                            (const bf16*)W2, (const bf16*)b2, Y1, Y2, N);
}

template <typename T>
__device__ __forceinline__ void proj1_body(
    u16* W1s, const T* X, const T* W, const T* b, bf16* Y, int N)
{
    int tid = threadIdx.x;
    for (int i = tid; i < DIM * DIM; i += 256) W1s[i] = f2bfu(ldf(W, i));
    __syncthreads();
    const u32* Wu = (const u32*)W1s;
    int lane = tid & 63, d0 = 2 * lane;
    float b10 = ldf(b, d0), b11 = ldf(b, d0 + 1);
    int wid = blockIdx.x * 4 + (tid >> 6);
    for (int n = wid * 4; n <= N - 4; n += GRID_P * 16) {
        float xA[4], xB[4], a0[4], a1[4];
#pragma unroll
        for (int t = 0; t < 4; ++t) {
            xA[t] = ldf(X, (size_t)(n + t) * DIM + d0);
            xB[t] = ldf(X, (size_t)(n + t) * DIM + d0 + 1);
            a0[t] = b10; a1[t] = b11;
        }
#pragma unroll
        for (int k2 = 0; k2 < 64; ++k2) {
            float2 wa = bfp(Wu[(2 * k2) * 64 + lane]);
            float2 wb = bfp(Wu[(2 * k2 + 1) * 64 + lane]);
#pragma unroll
            for (int t = 0; t < 4; ++t) {
                float x0 = rlf(xA[t], k2), x1 = rlf(xB[t], k2);
                a0[t] = fmaf(x0, wa.x, a0[t]); a1[t] = fmaf(x0, wa.y, a1[t]);
                a0[t] = fmaf(x1, wb.x, a0[t]); a1[t] = fmaf(x1, wb.y, a1[t]);
            }
        }
#pragma unroll
        for (int t = 0; t < 4; ++t) {
            Y[(size_t)(n + t) * DIM + d0]     = __float2bfloat16(a0[t]);
            Y[(size_t)(n + t) * DIM + d0 + 1] = __float2bfloat16(a1[t]);
        }
    }
}

__global__ __launch_bounds__(256, 2) void proj1_kernel(
    const int* __restrict__ flag, const void* X, const void* W, const void* b,
    bf16* __restrict__ Y, int N)
{
    __shared__ u16 W1s[DIM * DIM];
    if (flag[0]) proj1_body(W1s, (const float*)X, (const float*)W, (const float*)b, Y, N);
    else         proj1_body(W1s, (const bf16*)X, (const bf16*)W, (const bf16*)b, Y, N);
}

// out[n] = (A[n] / s[n,head]) @ W + b   (softmax denominator folded in)
template <typename T>
__device__ __forceinline__ void projout_body(
    u16* W1s, const float* A, const float* s, const T* W, const T* b,
    void* out, size_t off, int N)
{
    int tid = threadIdx.x;
    for (int i = tid; i < DIM * DIM; i += 256) W1s[i] = f2bfu(ldf(W, i));
    __syncthreads();
    const u32* Wu = (const u32*)W1s;
    int lane = tid & 63, d0 = 2 * lane, h = lane >> 4;
    float b10 = ldf(b, d0), b11 = ldf(b, d0 + 1);
    int wid = blockIdx.x * 4 + (tid >> 6);
    for (int n = wid * 4; n <= N - 4; n += GRID_P * 16) {
        float xA[4], xB[4], a0[4], a1[4];
#pragma unroll
        for (int t = 0; t < 4; ++t) {
            float inv = 1.0f / (s[(size_t)(n + t) * NH + h] + 1e-16f);
            xA[t] = A[(size_t)(n + t) * DIM + d0] * inv;
            xB[t] = A[(size_t)(n + t) * DIM + d0 + 1] * inv;
            a0[t] = b10; a1[t] = b11;
        }
#pragma unroll
        for (int k2 = 0; k2 < 64; ++k2) {
            float2 wa = bfp(Wu[(2 * k2) * 64 + lane]);
            float2 wb = bfp(Wu[(2 * k2 + 1) * 64 + lane]);
#pragma unroll
            for (int t = 0; t < 4; ++t) {
                float x0 = rlf(xA[t], k2), x1 = rlf(xB[t], k2);
                a0[t] = fmaf(x0, wa.x, a0[t]); a1[t] = fmaf(x0, wa.y, a1[t]);
                a0[t] = fmaf(x1, wb.x, a0[t]); a1[t] = fmaf(x1, wb.y, a1[t]);
            }
        }
#pragma unroll
        for (int t = 0; t < 4; ++t) {
            stf((T*)out + off, (size_t)(n + t) * DIM + d0, a0[t]);
            stf((T*)out + off, (size_t)(n + t) * DIM + d0 + 1, a1[t]);
        }
    }
}

__global__ __launch_bounds__(256, 2) void projout_kernel(
    const int* __restrict__ flag, const float* __restrict__ A, const float* __restrict__ s,
    const void* W, const void* b, void* out, size_t off, int N)
{
    __shared__ u16 W1s[DIM * DIM];
    if (flag[0]) projout_body(W1s, A, s, (const float*)W, (const float*)b, out, off, N);
    else         projout_body(W1s, A, s, (const bf16*)W, (const bf16*)b, out, off, N);
}

// ---------- gated edge kernel: LDS bf16 weights, 4 edges per wave-iteration ----------
template <typename T>
__device__ __forceinline__ void edge1_body(
    u16* W1s, u16* W2s,
    const bf16* Xs, const bf16* Xd,
    const int* src, const int* dst, const int* cat,
    const T* econt, const T* emb,
    const T* gW1, const T* gb1, const T* gW2, const T* gb2,
    const T* attn, float* s_out, float* aggr)
{
    int tid = threadIdx.x;
    for (int i = tid; i < 36 * DIM; i += 256) W1s[i] = f2bfu(ldf(gW1, i));
    for (int i = tid; i < DIM * DIM; i += 256) W2s[i] = f2bfu(ldf(gW2, i));
    __syncthreads();
    const u32* W1u = (const u32*)W1s;
    const u32* W2u = (const u32*)W2s;

    int lane = tid & 63, d0 = 2 * lane;
    int h = lane >> 4, k0 = d0 & 31;
    float b10 = ldf(gb1, d0), b11 = ldf(gb1, d0 + 1);
    float b20 = ldf(gb2, d0), b21 = ldf(gb2, d0 + 1);
    float av0 = ldf(attn, h * HDI + k0), av1 = ldf(attn, h * HDI + k0 + 1);
    const float rs = 0.17677669529663688110f;  // 1/sqrt(32)

    int wid = blockIdx.x * 4 + (tid >> 6);
    for (int e = wid * 4; e <= NE1 - 4; e += GRID_P * 16) {
        int si[4], di[4];
        float gfv[4];
#pragma unroll
        for (int t = 0; t < 4; ++t) {
            si[t] = src[e + t]; di[t] = dst[e + t];
            int c = cat[e + t];
            float g = 0.0f;
            if (lane < 32) g = ldf(emb, c * 32 + lane);
            else if (lane < 36) g = ldf(econt, (size_t)(e + t) * 4 + (lane - 32));
            gfv[t] = g;
        }

        // GEMM1 [36]->[128]; lane owns outputs d0,d0+1; weights shared across 4 edges
        float hA[4], hB[4];
        {
            float a0[4], a1[4];
#pragma unroll
            for (int t = 0; t < 4; ++t) { a0[t] = b10; a1[t] = b11; }
#pragma unroll
            for (int k = 0; k < 36; ++k) {
                float2 wv = bfp(W1u[k * 64 + lane]);
#pragma unroll
                for (int t = 0; t < 4; ++t) {
                    float sc = rlf(gfv[t], k);
                    a0[t] = fmaf(sc, wv.x, a0[t]);
                    a1[t] = fmaf(sc, wv.y, a1[t]);
                }
            }
#pragma unroll
            for (int t = 0; t < 4; ++t) {
                hA[t] = 0.5f * a0[t] * (1.0f + erff(a0[t] * 0.70710678118654752440f));
                hB[t] = 0.5f * a1[t] * (1.0f + erff(a1[t] * 0.70710678118654752440f));
            }
        }

        // GEMM2 [128]->[128]; h1[j]: even j in hA of lane j/2, odd j in hB
        float c0[4], c1[4];
#pragma unroll
        for (int t = 0; t < 4; ++t) { c0[t] = b20; c1[t] = b21; }
#pragma unroll
        for (int j2 = 0; j2 < 64; ++j2) {
            float2 w0 = bfp(W2u[(2 * j2) * 64 + lane]);
            float2 w1 = bfp(W2u[(2 * j2 + 1) * 64 + lane]);
#pragma unroll
            for (int t = 0; t < 4; ++t) {
                float h0 = rlf(hA[t], j2);
                float h1v = rlf(hB[t], j2);
                c0[t] = fmaf(h0, w0.x, c0[t]); c1[t] = fmaf(h0, w0.y, c1[t]);
                c0[t] = fmaf(h1v, w1.x, c0[t]); c1[t] = fmaf(h1v, w1.y, c1[t]);
            }
        }

        // epilogue per edge: message, logit, exp, atomics
#pragma unroll
        for (int t = 0; t < 4; ++t) {
            float gate0 = 1.0f / (1.0f + expf(-c0[t]));
            float gate1 = 1.0f / (1.0f + expf(-c1[t]));
            __hip_bfloat162 svv = *(const __hip_bfloat162*)&Xs[(size_t)si[t] * DIM + d0];
            __hip_bfloat162 dvv = *(const __hip_bfloat162*)&Xd[(size_t)di[t] * DIM + d0];
            float sx = b2f(svv.x), sy = b2f(svv.y);
            float dx = b2f(dvv.x), dy = b2f(dvv.y);
            float m0 = (sx + dx) * gate0;
            float m1 = (sy + dy) * gate1;

            float p = (sx * dx + sy * dy) * rs + m0 * av0 + m1 * av1;
            p += __shfl_xor(p, 8);
            p += __shfl_xor(p, 4);
            p += __shfl_xor(p, 2);
            p += __shfl_xor(p, 1);
            p = fminf(p, 80.0f);
            float ev = expf(p);

            if ((lane & 15) == 0)
                atomicAdd(&s_out[(size_t)di[t] * NH + h], ev);
            float* ap = &aggr[(size_t)di[t] * DIM + d0];
            atomicAdd(ap, ev * m0);
            atomicAdd(ap + 1, ev * m1);
        }
    }
}

__global__ __launch_bounds__(256, 2) void edge1_kernel(
    const int* __restrict__ flag,
    const bf16* __restrict__ Xs, const bf16* __restrict__ Xd,
    const int* __restrict__ src, const int* __restrict__ dst,
    const int* __restrict__ cat, const void* econt, const void* emb,
    const void* gW1, const void* gb1, const void* gW2, const void* gb2,
    const void* attn, float* __restrict__ s_out, float* __restrict__ aggr)
{
    __shared__ u16 W1s[36 * DIM];
    __shared__ u16 W2s[DIM * DIM];
    if (flag[0])
        edge1_body(W1s, W2s, Xs, Xd, src, dst, cat,
                   (const float*)econt, (const float*)emb,
                   (const float*)gW1, (const float*)gb1,
                   (const float*)gW2, (const float*)gb2,
                   (const float*)attn, s_out, aggr);
    else
        edge1_body(W1s, W2s, Xs, Xd, src, dst, cat,
                   (const bf16*)econt, (const bf16*)emb,
                   (const bf16*)gW1, (const bf16*)gb1,
                   (const bf16*)gW2, (const bf16*)gb2,
                   (const bf16*)attn, s_out, aggr);
}

// ---------- ungated edge kernel (no weights): one wave per edge ----------
template <typename T>
__device__ __forceinline__ void edge2_body(
    const bf16* Xs, const bf16* Xd,
    const int* src, const int* dst,
    const T* attn, float* s_out, float* aggr)
{
    int e = blockIdx.x;
    int lane = threadIdx.x;
    int si = src[e], di = dst[e];
    int d0 = lane * 2;
    int h = lane >> 4, k0 = d0 & 31;
    const float rs = 0.17677669529663688110f;

    __hip_bfloat162 svv = *(const __hip_bfloat162*)&Xs[(size_t)si * DIM + d0];
    __hip_bfloat162 dvv = *(const __hip_bfloat162*)&Xd[(size_t)di * DIM + d0];
    float sx = b2f(svv.x), sy = b2f(svv.y);
    float dx = b2f(dvv.x), dy = b2f(dvv.y);
    float m0 = sx + dx;
    float m1 = sy + dy;

    float p = (sx * dx + sy * dy) * rs
            + m0 * ldf(attn, h * HDI + k0) + m1 * ldf(attn, h * HDI + k0 + 1);
    p += __shfl_xor(p, 8);
    p += __shfl_xor(p, 4);
    p += __shfl_xor(p, 2);
    p += __shfl_xor(p, 1);
    p = fminf(p, 80.0f);
    float ev = expf(p);

    if ((lane & 15) == 0)
        atomicAdd(&s_out[(size_t)di * NH + h], ev);
    float* ap = &aggr[(size_t)di * DIM + d0];
    atomicAdd(ap, ev * m0);
    atomicAdd(ap + 1, ev * m1);
}

__global__ __launch_bounds__(64) void edge2_kernel(
    const int* __restrict__ flag,
    const bf16* __restrict__ Xs, const bf16* __restrict__ Xd,
    const int* __restrict__ src, const int* __restrict__ dst,
    const void* attn, float* __restrict__ s_out, float* __restrict__ aggr)
{
    if (flag[0]) edge2_body(Xs, Xd, src, dst, (const float*)attn, s_out, aggr);
    else         edge2_body(Xs, Xd, src, dst, (const bf16*)attn, s_out, aggr);
}

extern "C" void kernel_launch(void* const* d_in, const int* in_sizes, int n_in,
                              void* d_out, int out_size, void* d_ws, size_t ws_size,
                              hipStream_t stream)
{
    const void* x_drug  = d_in[0];
    const void* x_dis   = d_in[1];
    const void* e1_cont = d_in[2];
    const void* W_src1  = d_in[3];
    const void* b_src1  = d_in[4];
    const void* W_dst1  = d_in[5];
    const void* b_dst1  = d_in[6];
    const void* attn1   = d_in[7];
    const void* emb1    = d_in[8];
    const void* gW1     = d_in[9];
    const void* gb1     = d_in[10];
    const void* gW2     = d_in[11];
    const void* gb2     = d_in[12];
    const void* W_src2  = d_in[13];
    const void* b_src2  = d_in[14];
    const void* W_dst2  = d_in[15];
    const void* b_dst2  = d_in[16];
    const void* attn2   = d_in[17];
    const void* Wo_drug = d_in[18];
    const void* bo_drug = d_in[19];
    const void* Wo_dis  = d_in[20];
    const void* bo_dis  = d_in[21];
    const int* e1_src = (const int*)d_in[22];
    const int* e1_dst = (const int*)d_in[23];
    const int* e2_src = (const int*)d_in[24];
    const int* e2_dst = (const int*)d_in[25];
    const int* e1_cat = (const int*)d_in[26];

    // guard 1: input order/sizes (signature 77.0 if wrong)
    bool sizes_ok = (n_in == 27)
        && in_sizes[0] == ND * DIM && in_sizes[1] == NS * DIM
        && in_sizes[2] == NE1 * 4
        && in_sizes[3] == DIM * DIM && in_sizes[4] == DIM
        && in_sizes[5] == DIM * DIM && in_sizes[6] == DIM
        && in_sizes[7] == NH * HDI && in_sizes[8] == 8 * 32
        && in_sizes[9] == 36 * DIM && in_sizes[10] == DIM
        && in_sizes[11] == DIM * DIM && in_sizes[12] == DIM
        && in_sizes[13] == DIM * DIM && in_sizes[17] == NH * HDI
        && in_sizes[18] == DIM * DIM && in_sizes[20] == DIM * DIM
        && in_sizes[22] == NE1 && in_sizes[23] == NE1
        && in_sizes[24] == NE2 && in_sizes[25] == NE2 && in_sizes[26] == NE1;
    if (!sizes_ok) {
        size_t n = (size_t)out_size;
        fill16_kernel<<<(int)((n + 255) / 256), 256, 0, stream>>>((u16*)d_out, 0x429A, n);
        return;
    }

    // workspace layout: [flag 64B][Xs 25.6M][Xd 25.6M][sb 1.6M][aggr 51.2M]
    size_t off_Xs   = 64;
    size_t off_Xd   = off_Xs + (size_t)ND * DIM * 2;
    size_t off_sb   = off_Xd + (size_t)ND * DIM * 2;
    size_t off_aggr = off_sb + (size_t)ND * NH * 4;
    size_t need     = off_aggr + (size_t)ND * DIM * 4;
    if (ws_size < need) {
        size_t n = (size_t)out_size;
        fill16_kernel<<<(int)((n + 255) / 256), 256, 0, stream>>>((u16*)d_out, 0x42F6, n);
        return;
    }

    char* w = (char*)d_ws;
    int*   flag = (int*)w;
    bf16*  Xs   = (bf16*)(w + off_Xs);
    bf16*  Xd   = (bf16*)(w + off_Xd);
    float* sb   = (float*)(w + off_sb);
    float* aggr = (float*)(w + off_aggr);

    detect_kernel<<<1, 64, 0, stream>>>((const u16*)W_src1, flag);

    // ---- phase 1: drug -> drug (gated) ----
    hipMemsetAsync(sb, 0, (size_t)ND * NH * 4, stream);
    hipMemsetAsync(aggr, 0, (size_t)ND * DIM * 4, stream);
    proj2_kernel<<<GRID_P, 256, 0, stream>>>(flag, x_drug, W_src1, b_src1, W_dst1, b_dst1, Xs, Xd, ND);
    edge1_kernel<<<GRID_P, 256, 0, stream>>>(
        flag, Xs, Xd, e1_src, e1_dst, e1_cat, e1_cont, emb1,
        gW1, gb1, gW2, gb2, attn1, sb, aggr);
    projout_kernel<<<GRID_P, 256, 0, stream>>>(flag, aggr, sb, Wo_drug, bo_drug, d_out, 0, ND);

    // ---- phase 2: drug -> disease (no gate) ----
    hipMemsetAsync(sb, 0, (size_t)NS * NH * 4, stream);
    hipMemsetAsync(aggr, 0, (size_t)NS * DIM * 4, stream);
    proj1_kernel<<<GRID_P, 256, 0, stream>>>(flag, x_drug, W_src2, b_src2, Xs, ND);
    proj1_kernel<<<GRID_P, 256, 0, stream>>>(flag, x_dis, W_dst2, b_dst2, Xd, NS);
    edge2_kernel<<<NE2, 64, 0, stream>>>(flag, Xs, Xd, e2_src, e2_dst, attn2, sb, aggr);
    projout_kernel<<<GRID_P, 256, 0, stream>>>(flag, aggr, sb, Wo_dis, bo_dis, d_out, (size_t)ND * DIM, NS);
}